// Round 1
// baseline (370.207 us; speedup 1.0000x reference)
//
#include <hip/hip_runtime.h>

// TT-chain: N=65536, L=128, D=4, R=8, O=2.
//   m = x[n,0] @ core_first[0]
//   for c in 0..125: m[l] = sum_{k,j} m[k]*cm[c,k,j,l]*x[n,c+1,j]
//   out[n,:] = sum_{k,j} m[k]*cl[k,j,:]*x[n,127,j]
// cm[:, :, 3, :] == I -> j=3 term is x.w*m[l].
//
// R6 design: the cores are WAVE-UNIFORM, so feed them through SGPRs
// (s_load_dwordx8/x16 via constant cache), not LDS broadcast reads.
// R5 paid ~1150 LDS-cycles per CU-step (24 broadcast ds_read_b128 x 4
// waves) against only ~448 VALU cycles per SIMD-step -> LDS was the wall
// and VALUBusy sat at 33%. With scalar-operand v_fmac_f32
// (v_nm += s_core * v_p, one SGPR read per VALU instr: legal), there is
// no LDS, no __syncthreads, no pack kernel, and full fp32 precision.
// Occupancy is grid-limited at 1 wave/SIMD (N/64 = 1024 waves on 256 CUs),
// so x is prefetched 8 float4 deep in registers (VGPRs are free at this
// occupancy) and the chunk loop is kept rolled (#pragma unroll 1) so the
// ~15 KB body fits I$ instead of a 15x-unrolled ~200 KB stream.
//
// Cycle model: 224 VALU ops/step * 2 cyc = 448 cyc/SIMD-step; 126 steps
// ~ 56k cyc ~ 23.5 us. HBM floor: 134 MB / 6.3 TB/s ~ 21.3 us. Balanced.

#define NTHREADS 256

__global__ __launch_bounds__(NTHREADS, 1) void tt_chain_s(
    const float* __restrict__ x,       // [N,128,4]
    const float* __restrict__ cm,      // [126,8,4,8]
    const float* __restrict__ cf,      // [1,4,8]
    const float* __restrict__ cl,      // [8,4,2]
    float* __restrict__ out)           // [N,2]
{
    const int tid = threadIdx.x;
    const int n = blockIdx.x * NTHREADS + tid;   // grid covers N exactly

    const float4* __restrict__ xr = reinterpret_cast<const float4*>(x) + (size_t)n * 128;

    // ---- prologue: init m from core_first, prime x prefetch ----
    const float4 x0 = xr[0];
    float4 cur[8], nxt[8];
    #pragma unroll
    for (int i = 0; i < 8; ++i) cur[i] = xr[1 + i];

    float m[8];
    #pragma unroll
    for (int k = 0; k < 8; ++k)
        m[k] = fmaf(cf[k], x0.x,
               fmaf(cf[8 + k], x0.y,
               fmaf(cf[16 + k], x0.z, cf[24 + k] * x0.w)));

    // one recurrence step; Bs = &cm[c*256], wave-uniform (loop-constant)
    // address -> scalar loads. Layout: Bs[k*32 + j*8 + l], j<3 used.
    auto step = [&](const float* __restrict__ Bs, const float4 xt) {
        float nm[8];
        #pragma unroll
        for (int l = 0; l < 8; ++l) nm[l] = xt.w * m[l];   // j=3 identity
        #pragma unroll
        for (int k = 0; k < 8; ++k) {
            const float p0 = m[k] * xt.x;
            const float p1 = m[k] * xt.y;
            const float p2 = m[k] * xt.z;
            const float* __restrict__ Bk = Bs + k * 32;
            #pragma unroll
            for (int l = 0; l < 8; ++l) {
                nm[l] = fmaf(p0, Bk[l],      nm[l]);
                nm[l] = fmaf(p1, Bk[8 + l],  nm[l]);
                nm[l] = fmaf(p2, Bk[16 + l], nm[l]);
            }
        }
        #pragma unroll
        for (int l = 0; l < 8; ++l) m[l] = nm[l];
    };

    // ---- chunks 0..14: 8 steps each, prefetch x for chunk ch+1 ----
    #pragma unroll 1
    for (int ch = 0; ch < 15; ++ch) {
        #pragma unroll
        for (int i = 0; i < 8; ++i) {
            int t = (ch + 1) * 8 + 1 + i;
            if (t > 127) t = 127;     // harmless re-read of last row
            nxt[i] = xr[t];
        }

        const float* __restrict__ B = cm + (size_t)ch * (8 * 256);
        #pragma unroll
        for (int s = 0; s < 8; ++s) step(B + s * 256, cur[s]);

        #pragma unroll
        for (int i = 0; i < 8; ++i) cur[i] = nxt[i];
    }

    // ---- tail: steps c=120..125 (xt = cur[0..5]) ----
    {
        const float* __restrict__ B = cm + (size_t)120 * 256;
        #pragma unroll
        for (int s = 0; s < 6; ++s) step(B + s * 256, cur[s]);
    }

    // ---- epilogue: out[n,o] = sum_{k,j} m[k]*cl[k*8+j*2+o]*x[n,127,j] ----
    {
        const float4 xl = cur[6];   // xr[127]
        const float xj[4] = { xl.x, xl.y, xl.z, xl.w };
        float o0 = 0.f, o1 = 0.f;
        #pragma unroll
        for (int j = 0; j < 4; ++j) {
            float v0 = 0.f, v1 = 0.f;
            #pragma unroll
            for (int k = 0; k < 8; ++k) {
                v0 = fmaf(m[k], cl[k * 8 + j * 2 + 0], v0);
                v1 = fmaf(m[k], cl[k * 8 + j * 2 + 1], v1);
            }
            o0 = fmaf(xj[j], v0, o0);
            o1 = fmaf(xj[j], v1, o1);
        }
        reinterpret_cast<float2*>(out)[n] = make_float2(o0, o1);
    }
}

extern "C" void kernel_launch(void* const* d_in, const int* in_sizes, int n_in,
                              void* d_out, int out_size, void* d_ws, size_t ws_size,
                              hipStream_t stream) {
    const float* x  = (const float*)d_in[0];   // [N,128,4]
    const float* cf = (const float*)d_in[1];   // [1,4,8]
    const float* cm = (const float*)d_in[2];   // [126,8,4,8]
    const float* cl = (const float*)d_in[3];   // [8,4,2]
    float* out = (float*)d_out;                // [N,2]

    const int N = in_sizes[0] / (128 * 4);

    tt_chain_s<<<N / NTHREADS, NTHREADS, 0, stream>>>(x, cm, cf, cl, out);
}

// Round 3
// 296.918 us; speedup vs baseline: 1.2468x; 1.2468x over previous
//
#include <hip/hip_runtime.h>

// TT-chain: N=65536, L=128, D=4, R=8, O=2.
//   m = x[n,0] @ core_first[0]
//   for c in 0..125: m[l] = sum_{k,j} m[k]*cm[c,k,j,l]*x[n,c+1,j]
//   out[n,:] = sum_{k,j} m[k]*cl[k,j,:]*x[n,127,j]
// cm[:, :, 3, :] == I -> j=3 term is x.w*m[l] (exact fp32 path).
//
// R8 == R7 resubmitted (R7's bench died on container acquisition, not on
// the kernel -- no counters were produced).
//
// R7 design: broadcast the wave-uniform cores via VMEM->VGPR + v_readlane.
//   R5 (LDS broadcast): ds_read_b128 pays the 64-lane return bus -> ~1150
//     LDS cyc/CU-step wall -> 140 us.
//   R6 (s_load/SGPR): 192 floats/step >> ~100 SGPRs -> compiler serializes
//     load->waitcnt->consume, ~5 exposed scalar-mem latencies/step at
//     1 wave/SIMD -> 4900 cyc/step -> 257 us.
//   R7: per-lane COALESCED global loads stage each chunk's packed cores in
//     VGPRs (capacity is ~free at 1 wave/SIMD; register double-buffered a
//     full chunk ahead -> latency fully hidden), then v_readlane (plain
//     VALU, VGPR source, zero latency to hide) broadcasts each value at
//     consumption. Cores packed as fp16 PAIRS: one readlane feeds two
//     v_fma_mix_f32 (full-rate mixed fp16xfp32 fma). No LDS, no barriers.
//     m and the identity (j=3) chain stay fp32 -- same quantization R5
//     passed with.
//
// Cycle model per SIMD-step: 8 mul + 24 mul + 96 readlane + 192 fma_mix
// ~ 328 VALU ops x 2 cyc ~ 656 cyc; 126 steps ~ 83k cyc ~ 34 us.
// HBM floor 134 MB / 6.3 TB/s ~ 21 us (overlapped). VALU-bound by design.

#define NTHREADS 256

typedef _Float16 h2 __attribute__((ext_vector_type(2)));

// Pack cm[126,8,4,8] (fp32) -> cmp dwords [126][96]; dword d = k*12+j*4+u
// holds halfs (l=2u, l=2u+1), j<3 only.
__global__ __launch_bounds__(NTHREADS) void pack_cores_p(
    const float* __restrict__ cm, unsigned int* __restrict__ cmp)
{
    int t = blockIdx.x * NTHREADS + threadIdx.x;
    if (t >= 126 * 96) return;
    int c = t / 96;
    int d = t % 96;           // k*12 + j*4 + u
    int k = d / 12;
    int r = d % 12;
    int j = r / 4;
    int u = r % 4;
    const float f0 = cm[c * 256 + k * 32 + j * 8 + 2 * u + 0];
    const float f1 = cm[c * 256 + k * 32 + j * 8 + 2 * u + 1];
    h2 h; h.x = (_Float16)f0; h.y = (_Float16)f1;
    cmp[t] = __builtin_bit_cast(unsigned int, h);
}

// One recurrence step S (0..7 within a chunk). vC = 12 VGPRs holding the
// chunk's 768 packed dwords across the wave's 64 lanes: dword i of the
// chunk lives in vC[i>>6], lane (i&63). readlane broadcasts it.
template<int S>
__device__ __forceinline__ void do_step(const int (&vC)[12], const float4 xt,
                                        float (&m)[8])
{
    float nm[8];
    #pragma unroll
    for (int l = 0; l < 8; ++l) nm[l] = xt.w * m[l];   // j=3 identity, fp32
    #pragma unroll
    for (int k = 0; k < 8; ++k) {
        const float p[3] = { m[k] * xt.x, m[k] * xt.y, m[k] * xt.z };
        #pragma unroll
        for (int j = 0; j < 3; ++j) {
            #pragma unroll
            for (int u = 0; u < 4; ++u) {
                const int d = S * 96 + k * 12 + j * 4 + u;
                const int sv = __builtin_amdgcn_readlane(vC[d >> 6], d & 63);
                const h2 h = __builtin_bit_cast(h2, sv);
                nm[2 * u + 0] = fmaf((float)h.x, p[j], nm[2 * u + 0]);
                nm[2 * u + 1] = fmaf((float)h.y, p[j], nm[2 * u + 1]);
            }
        }
    }
    #pragma unroll
    for (int l = 0; l < 8; ++l) m[l] = nm[l];
}

__global__ __launch_bounds__(NTHREADS, 1) void tt_chain_r(
    const float* __restrict__ x,          // [N,128,4]
    const int* __restrict__ cpk,          // packed cores, [126*96] dwords (+pad)
    const float* __restrict__ cf,         // [1,4,8]
    const float* __restrict__ cl,         // [8,4,2]
    float* __restrict__ out)              // [N,2]
{
    const int tid = threadIdx.x;
    const int n = blockIdx.x * NTHREADS + tid;   // grid covers N exactly
    const int ln = tid & 63;                     // hardware lane

    const float4* __restrict__ xr = reinterpret_cast<const float4*>(x) + (size_t)n * 128;

    // ---- prologue: init m, prime x + core prefetch (chunk 0) ----
    const float4 x0 = xr[0];
    float4 cur[8], nxt[8];
    #pragma unroll
    for (int i = 0; i < 8; ++i) cur[i] = xr[1 + i];

    int vC[12], vN[12];
    #pragma unroll
    for (int i = 0; i < 12; ++i) vC[i] = cpk[i * 64 + ln];

    float m[8];
    #pragma unroll
    for (int k = 0; k < 8; ++k)
        m[k] = fmaf(cf[k], x0.x,
               fmaf(cf[8 + k], x0.y,
               fmaf(cf[16 + k], x0.z, cf[24 + k] * x0.w)));

    // ---- chunks 0..14: 8 steps each; prefetch x and cores for ch+1 ----
    #pragma unroll 1
    for (int ch = 0; ch < 15; ++ch) {
        #pragma unroll
        for (int i = 0; i < 12; ++i)
            vN[i] = cpk[(ch + 1) * 768 + i * 64 + ln];   // ch15 overreads 768B pad
        #pragma unroll
        for (int i = 0; i < 8; ++i) {
            int t = (ch + 1) * 8 + 1 + i;
            if (t > 127) t = 127;     // harmless re-read of last row
            nxt[i] = xr[t];
        }

        do_step<0>(vC, cur[0], m);
        do_step<1>(vC, cur[1], m);
        do_step<2>(vC, cur[2], m);
        do_step<3>(vC, cur[3], m);
        do_step<4>(vC, cur[4], m);
        do_step<5>(vC, cur[5], m);
        do_step<6>(vC, cur[6], m);
        do_step<7>(vC, cur[7], m);

        #pragma unroll
        for (int i = 0; i < 8; ++i) cur[i] = nxt[i];
        #pragma unroll
        for (int i = 0; i < 12; ++i) vC[i] = vN[i];
    }

    // ---- tail chunk 15: steps c=120..125 (xt = cur[0..5]) ----
    do_step<0>(vC, cur[0], m);
    do_step<1>(vC, cur[1], m);
    do_step<2>(vC, cur[2], m);
    do_step<3>(vC, cur[3], m);
    do_step<4>(vC, cur[4], m);
    do_step<5>(vC, cur[5], m);

    // ---- epilogue: out[n,o] = sum_{k,j} m[k]*cl[k*8+j*2+o]*x[n,127,j] ----
    {
        const float4 xl = cur[6];   // xr[127]
        const float xj[4] = { xl.x, xl.y, xl.z, xl.w };
        float o0 = 0.f, o1 = 0.f;
        #pragma unroll
        for (int j = 0; j < 4; ++j) {
            float v0 = 0.f, v1 = 0.f;
            #pragma unroll
            for (int k = 0; k < 8; ++k) {
                v0 = fmaf(m[k], cl[k * 8 + j * 2 + 0], v0);
                v1 = fmaf(m[k], cl[k * 8 + j * 2 + 1], v1);
            }
            o0 = fmaf(xj[j], v0, o0);
            o1 = fmaf(xj[j], v1, o1);
        }
        reinterpret_cast<float2*>(out)[n] = make_float2(o0, o1);
    }
}

extern "C" void kernel_launch(void* const* d_in, const int* in_sizes, int n_in,
                              void* d_out, int out_size, void* d_ws, size_t ws_size,
                              hipStream_t stream) {
    const float* x  = (const float*)d_in[0];   // [N,128,4]
    const float* cf = (const float*)d_in[1];   // [1,4,8]
    const float* cm = (const float*)d_in[2];   // [126,8,4,8]
    const float* cl = (const float*)d_in[3];   // [8,4,2]
    float* out = (float*)d_out;                // [N,2]

    const int N = in_sizes[0] / (128 * 4);

    // packed cores: 126*96 dwords = 48384 B; chunk-15 prefetch overreads
    // 768 B of pad (steps 126,127 never consumed).
    unsigned int* cmp = (unsigned int*)d_ws;

    pack_cores_p<<<(126 * 96 + NTHREADS - 1) / NTHREADS, NTHREADS, 0, stream>>>(cm, cmp);

    tt_chain_r<<<N / NTHREADS, NTHREADS, 0, stream>>>(x, (const int*)cmp, cf, cl, out);
}

// Round 4
// 253.822 us; speedup vs baseline: 1.4585x; 1.1698x over previous
//
#include <hip/hip_runtime.h>

// TT-chain: N=65536, L=128, D=4, R=8, O=2.
//   m = x[n,0] @ core_first[0]
//   for c in 0..125: m[l] = sum_{k,j} m[k]*cm[c,k,j,l]*x[n,c+1,j]
//   out[n,:] = sum_{k,j} m[k]*cl[k,j,:]*x[n,127,j]
// cm[:, :, 3, :] == I -> j=3 term is x.w*m[l]; full fp32 (exact).
//
// R9 design: rolled, I$-resident step loop + fp32 readlane broadcast.
//   Post-mortem of R5/R6/R8: every variant's fully-unrolled chunk body was
//   ~19-33 KB of straight-line code (R8: ~33 KB > 32 KB I$), and R8's
//   VGPR_Count=56 proves the compiler sank the prefetch loads next to
//   their uses (the source needed ~110 live VGPRs). At 1 wave/SIMD both
//   I$ refetch bubbles and exposed load latency are unhidable -> all
//   variants landed 2-4x above their VALU models.
//   Fix: stage cores PER-STEP (192 fp32 = exactly 3 lane-distributed
//   VGPRs), so the 126-step loop stays rolled with compile-time readlane
//   reg/lane indices inside one step. Body ~3.4 KB: I$-resident. fp32
//   cores: each value = 1 v_readlane + 1 v_fma (SGPR operand), zero
//   conversions. Pipeline: cores prefetched 1 step ahead (L2-hot, ~200cy
//   << ~850cy step), x rows 3 steps ahead (~2500cy covers ~900cy HBM).
//
// Cycle model per SIMD-step: 192 readlane + 192 fma + 32 mul + 4 loads +
// ~14 rotate/loop ~ 434 instr x 2 cyc ~ 870 cyc; 126 steps ~ 110k cyc
// ~ 46 us. HBM: 128 MB / 46 us = 2.8 TB/s < 6.3 roof. VALU-bound.

#define NTHREADS 256

// Pack cm[126,8,4,8] (fp32) -> cpk[c*192 + (k*24 + j*8 + l)], j<3 only.
__global__ __launch_bounds__(NTHREADS) void pack_cores_f(
    const float* __restrict__ cm, float* __restrict__ cpk)
{
    int t = blockIdx.x * NTHREADS + threadIdx.x;
    if (t >= 126 * 192) return;
    int c = t / 192;
    int d = t % 192;          // k*24 + j*8 + l
    int k = d / 24;
    int r = d % 24;
    int j = r / 8;
    int l = r % 8;
    cpk[t] = cm[c * 256 + k * 32 + j * 8 + l];
}

__global__ __launch_bounds__(NTHREADS, 1) void tt_chain_f(
    const float* __restrict__ x,          // [N,128,4]
    const int* __restrict__ cpk,          // packed cores [126*192] dwords
    const float* __restrict__ cf,         // [1,4,8]
    const float* __restrict__ cl,         // [8,4,2]
    float* __restrict__ out)              // [N,2]
{
    const int tid = threadIdx.x;
    const int n = blockIdx.x * NTHREADS + tid;   // grid covers N exactly
    const int ln = tid & 63;                     // hardware lane

    const float4* __restrict__ xr = reinterpret_cast<const float4*>(x) + (size_t)n * 128;

    // ---- prologue ----
    const float4 x0 = xr[0];

    // core staging: step s lives in 3 lane-distributed dwords
    // cpk[s*192 + r*64 + ln], r = 0..2
    int vC[3], vN[3];
    #pragma unroll
    for (int r = 0; r < 3; ++r) vC[r] = cpk[r * 64 + ln];          // step 0
    #pragma unroll
    for (int r = 0; r < 3; ++r) vN[r] = cpk[192 + r * 64 + ln];    // step 1

    // x pipeline: xc = row(c+1) (consumed by step c), +2 rows in flight
    float4 xc  = xr[1];
    float4 xn1 = xr[2];
    float4 xn2 = xr[3];

    float m[8];
    #pragma unroll
    for (int k = 0; k < 8; ++k)
        m[k] = fmaf(cf[k], x0.x,
               fmaf(cf[8 + k], x0.y,
               fmaf(cf[16 + k], x0.z, cf[24 + k] * x0.w)));

    // ---- rolled step loop: c = 0..125, body ~3.4 KB (I$-resident) ----
    #pragma unroll 1
    for (int c = 0; c < 126; ++c) {
        // compute step c from vC (cores) and xc (row c+1)
        float nm[8];
        #pragma unroll
        for (int l = 0; l < 8; ++l) nm[l] = xc.w * m[l];   // j=3 identity
        #pragma unroll
        for (int k = 0; k < 8; ++k) {
            const float p0 = m[k] * xc.x;
            const float p1 = m[k] * xc.y;
            const float p2 = m[k] * xc.z;
            #pragma unroll
            for (int j = 0; j < 3; ++j) {
                const float pj = (j == 0) ? p0 : (j == 1) ? p1 : p2;
                #pragma unroll
                for (int l = 0; l < 8; ++l) {
                    const int d = k * 24 + j * 8 + l;      // compile-time
                    const float cv = __builtin_bit_cast(float,
                        __builtin_amdgcn_readlane(vC[d >> 6], d & 63));
                    nm[l] = fmaf(pj, cv, nm[l]);
                }
            }
        }
        #pragma unroll
        for (int l = 0; l < 8; ++l) m[l] = nm[l];

        // rotate pipelines, then issue next prefetches
        #pragma unroll
        for (int r = 0; r < 3; ++r) vC[r] = vN[r];
        xc = xn1; xn1 = xn2;

        const int cn = (c + 2 < 126) ? c + 2 : 125;        // core step c+2
        #pragma unroll
        for (int r = 0; r < 3; ++r) vN[r] = cpk[cn * 192 + r * 64 + ln];
        const int tx = (c + 4 < 128) ? c + 4 : 127;        // x row c+4
        xn2 = xr[tx];
    }

    // ---- epilogue: xc = row 127 after final rotation ----
    {
        const float xj[4] = { xc.x, xc.y, xc.z, xc.w };
        float o0 = 0.f, o1 = 0.f;
        #pragma unroll
        for (int j = 0; j < 4; ++j) {
            float v0 = 0.f, v1 = 0.f;
            #pragma unroll
            for (int k = 0; k < 8; ++k) {
                v0 = fmaf(m[k], cl[k * 8 + j * 2 + 0], v0);
                v1 = fmaf(m[k], cl[k * 8 + j * 2 + 1], v1);
            }
            o0 = fmaf(xj[j], v0, o0);
            o1 = fmaf(xj[j], v1, o1);
        }
        reinterpret_cast<float2*>(out)[n] = make_float2(o0, o1);
    }
}

extern "C" void kernel_launch(void* const* d_in, const int* in_sizes, int n_in,
                              void* d_out, int out_size, void* d_ws, size_t ws_size,
                              hipStream_t stream) {
    const float* x  = (const float*)d_in[0];   // [N,128,4]
    const float* cf = (const float*)d_in[1];   // [1,4,8]
    const float* cm = (const float*)d_in[2];   // [126,8,4,8]
    const float* cl = (const float*)d_in[3];   // [8,4,2]
    float* out = (float*)d_out;                // [N,2]

    const int N = in_sizes[0] / (128 * 4);

    // packed fp32 cores: 126*192*4 = 96768 B in workspace
    float* cpk = (float*)d_ws;

    pack_cores_f<<<(126 * 192 + NTHREADS - 1) / NTHREADS, NTHREADS, 0, stream>>>(cm, cpk);

    tt_chain_f<<<N / NTHREADS, NTHREADS, 0, stream>>>(x, (const int*)cpk, cf, cl, out);
}